// Round 9
// baseline (121.104 us; speedup 1.0000x reference)
//
#include <hip/hip_runtime.h>
#include <math.h>

#define N_ATOMS 131072
#define N_MOLS  4096
#define DFEAT   128
#define NK      11
#define KDIM3   384          // 3 * DFEAT: [Sr | Sxr | Sxxr] blocks
#define N_DEPTH 128
#define EPS_F   1e-7f
#define SCAN_BLOCKS (N_ATOMS / 256)   // 512

__constant__ float c_means[NK] = {-1.645f, -1.08f, -0.739f, -0.468f, -0.228f,
                                  0.0f, 0.228f, 0.468f, 0.739f, 1.08f, 1.645f};
__constant__ float c_stds[NK]  = {0.283f, 0.17f, 0.134f, 0.118f, 0.114f,
                                  0.114f, 0.114f, 0.118f, 0.134f, 0.17f, 0.283f};

// Math (verified passing, rounds 2/5/7/8):
//   o_k(x) = 1 + a_k (x - m_k)^2,  a_k = 0.5 / (s_k^2 * log(s_k*sqrt(2pi))) < 0
//   den(x) = sum_k o_k + EPS = C2 x^2 + C1 x + C0   (always <= -178, rcp-safe)
//   (o_k+EPS)/den = coef0(k)*r + coef1(k)*(x r) + coef2(k)*(x^2 r),  r = 1/den
//   => segment sum needs only Sr, Sxr, Sxxr per (mol, feature);
//      W folds into Bt[384][128] once per launch.

// ---------------------------------------------------------------------------
// Kernel 1: (a) blocks < 192: fold W into Bt[384][128];
//           (b) blocks >= 192: scan-based offsets (1 coalesced latency
//               exposure instead of a 17-deep serial binary search).
// ---------------------------------------------------------------------------
__global__ __launch_bounds__(256) void wxform_offsets_kernel(
    const float* __restrict__ W,        // [DFEAT*NK, N_DEPTH]
    const int*   __restrict__ split,    // [N_ATOMS], sorted
    float*       __restrict__ Bt,       // [KDIM3, N_DEPTH]
    int*         __restrict__ offsets) {// [N_MOLS+1]
  const int bid = blockIdx.x;
  const int tid = threadIdx.x;
  if (bid < 192) {
    int t = bid * 256 + tid;            // 0..49151
    int n = t & 127;
    int row = t >> 7;                   // 0..383
    int j = row >> 7;                   // 0..2 (uniform per wave)
    int d = row & 127;
    float acc = 0.0f;
#pragma unroll
    for (int k = 0; k < NK; ++k) {
      float m = c_means[k], s = c_stds[k];
      float a = 0.5f / (s * s * logf(s * 2.5066282746310002f));
      float coef = (j == 2) ? a
                 : (j == 1) ? (-2.0f * a * m)
                            : fmaf(a, m * m, 1.0f + EPS_F);
      acc = fmaf(coef, W[(size_t)(d * NK + k) * N_DEPTH + n], acc);
    }
    Bt[(size_t)row * N_DEPTH + n] = acc;
  } else {
    int a = (bid - 192) * 256 + tid;    // atom index 0..N_ATOMS-1
    int cur  = split[a];
    int prev = (a == 0) ? -1 : split[a - 1];
    for (int j = prev + 1; j <= cur; ++j) offsets[j] = a;
    if (a == N_ATOMS - 1)
      for (int j = cur + 1; j <= N_MOLS; ++j) offsets[j] = N_ATOMS;
  }
}

// ---------------------------------------------------------------------------
// Kernel 2: sums only. 256 threads = 4 waves; wave w owns molecule bid*4+w.
// Lanes 0-31 even atoms, 32-63 odd atoms (wave load = 2 contiguous rows,
// coalesced). 12 register accumulators/lane; combine = 12 shfl_xor(32).
// ZERO LDS, ZERO barriers. 1024 blocks -> 8 blocks/CU = 32 waves/CU.
// Writes S[mol][384] (6.3 MB, stays in L2/L3 for kernel 3).
// ---------------------------------------------------------------------------
__global__ __launch_bounds__(256, 8) void sums_kernel(
    const float* __restrict__ x,        // [N_ATOMS, DFEAT]
    const int*   __restrict__ offsets,  // [N_MOLS+1]
    float*       __restrict__ S) {      // [N_MOLS, KDIM3]
  const int tid  = threadIdx.x;
  const int w    = tid >> 6;            // wave id 0..3
  const int lane = tid & 63;
  const int fq   = lane & 31;           // feature quad
  const int h    = lane >> 5;           // atom parity 0/1
  const int mol  = blockIdx.x * 4 + w;

  // Horner coefficients for den = sum_k o_k + EPS (uniform, tiny)
  float C2 = 0.0f, C1 = 0.0f, C0 = 11.0f + EPS_F;
#pragma unroll
  for (int k = 0; k < NK; ++k) {
    float m_ = c_means[k], s_ = c_stds[k];
    float a = 0.5f / (s_ * s_ * logf(s_ * 2.5066282746310002f));
    C2 += a;
    C1 = fmaf(-2.0f * a, m_, C1);
    C0 = fmaf(a, m_ * m_, C0);
  }

  const int start = offsets[mol];
  const int end   = offsets[mol + 1];

  float Sr[4]   = {0.f, 0.f, 0.f, 0.f};
  float Sxr[4]  = {0.f, 0.f, 0.f, 0.f};
  float Sxxr[4] = {0.f, 0.f, 0.f, 0.f};

  const float* xp = x + fq * 4;

  auto proc = [&](float4 v) {
    float xv[4] = {v.x, v.y, v.z, v.w};
#pragma unroll
    for (int q = 0; q < 4; ++q) {
      float den = fmaf(fmaf(C2, xv[q], C1), xv[q], C0);
      float r   = __builtin_amdgcn_rcpf(den);   // den <= -178 always
      float u   = xv[q] * r;
      Sr[q]  += r;
      Sxr[q] += u;
      Sxxr[q] = fmaf(xv[q], u, Sxxr[q]);
    }
  };

  int a = start + h;
  for (; a + 6 < end; a += 8) {         // x4 unroll: 4 KB in flight per wave
    float4 v0 = *(const float4*)&xp[(size_t)(a + 0) * DFEAT];
    float4 v1 = *(const float4*)&xp[(size_t)(a + 2) * DFEAT];
    float4 v2 = *(const float4*)&xp[(size_t)(a + 4) * DFEAT];
    float4 v3 = *(const float4*)&xp[(size_t)(a + 6) * DFEAT];
    proc(v0); proc(v1); proc(v2); proc(v3);
  }
  for (; a < end; a += 2) {
    float4 v = *(const float4*)&xp[(size_t)a * DFEAT];
    proc(v);
  }

  // Cross-half combine in-register: lane <-> lane^32.
#pragma unroll
  for (int q = 0; q < 4; ++q) {
    Sr[q]   += __shfl_xor(Sr[q],   32, 64);
    Sxr[q]  += __shfl_xor(Sxr[q],  32, 64);
    Sxxr[q] += __shfl_xor(Sxxr[q], 32, 64);
  }

  if (h == 0) {   // lanes 0-31 hold the full molecule sums
    float* Sp = S + (size_t)mol * KDIM3;
    *(float4*)&Sp[fq * 4]             = make_float4(Sr[0],  Sr[1],  Sr[2],  Sr[3]);
    *(float4*)&Sp[DFEAT + fq * 4]     = make_float4(Sxr[0], Sxr[1], Sxr[2], Sxr[3]);
    *(float4*)&Sp[2 * DFEAT + fq * 4] = make_float4(Sxxr[0],Sxxr[1],Sxxr[2],Sxxr[3]);
  }
}

// ---------------------------------------------------------------------------
// Kernel 3: out[4096,128] = tanh(S @ Bt + b). ZERO LDS, ZERO barriers.
// A-side (S rows) is wave-uniform -> readfirstlane'd pointer -> scalar
// s_load path (free: scalar pipe, no VALU/LDS cost). B-side per-lane
// coalesced dword loads (256 B/wave segments, L2-resident 196 KB table).
// 512 blocks x 256 thr: thread = (col n, half isub) computes 4 rows.
// VALU: 1536 fma/thread -> 2.6 us chip-wide floor.
// ---------------------------------------------------------------------------
__global__ __launch_bounds__(256) void gemm_bias_tanh_kernel(
    const float* __restrict__ S,        // [N_MOLS, KDIM3]
    const float* __restrict__ Bt,       // [KDIM3, N_DEPTH]
    const float* __restrict__ bias,     // [N_DEPTH]
    float*       __restrict__ out) {    // [N_MOLS, N_DEPTH]
  const int tid  = threadIdx.x;
  const int n    = tid & 127;           // output column
  const int isub = tid >> 7;            // 0..1 (uniform per wave)
  const int m0   = blockIdx.x * 8;

  const float* Sp[4];
#pragma unroll
  for (int j = 0; j < 4; ++j) {
    // readfirstlane -> provably wave-uniform -> SGPR pointer -> s_load
    int molu = __builtin_amdgcn_readfirstlane(m0 + isub * 4 + j);
    Sp[j] = S + (size_t)molu * KDIM3;
  }

  float acc[4] = {0.f, 0.f, 0.f, 0.f};

#pragma unroll 1
  for (int kt = 0; kt < KDIM3; kt += 8) {
    float b[8];
#pragma unroll
    for (int t = 0; t < 8; ++t)
      b[t] = Bt[(size_t)(kt + t) * N_DEPTH + n];
#pragma unroll
    for (int j = 0; j < 4; ++j) {
#pragma unroll
      for (int t = 0; t < 8; ++t)
        acc[j] = fmaf(Sp[j][kt + t], b[t], acc[j]);
    }
  }

  float bv = bias[n];
#pragma unroll
  for (int j = 0; j < 4; ++j) {
    int row = m0 + isub * 4 + j;
    out[(size_t)row * N_DEPTH + n] = tanhf(acc[j] + bv);
  }
}

// ---------------------------------------------------------------------------
extern "C" void kernel_launch(void* const* d_in, const int* in_sizes, int n_in,
                              void* d_out, int out_size, void* d_ws, size_t ws_size,
                              hipStream_t stream) {
  const float* x     = (const float*)d_in[0];  // [131072, 128] f32
  const int*   split = (const int*)d_in[1];    // [131072] int (sorted)
  const float* W     = (const float*)d_in[2];  // [1408, 128] f32
  const float* bias  = (const float*)d_in[3];  // [128] f32
  float* out = (float*)d_out;                  // [4096, 128] f32

  // Workspace: S[4096*384] f32, Bt[384*128] f32, offsets[4097] int (~6.5 MB)
  float* S       = (float*)d_ws;
  float* Bt      = (float*)((char*)d_ws + (size_t)N_MOLS * KDIM3 * 4);
  int*   offsets = (int*)((char*)Bt + (size_t)KDIM3 * N_DEPTH * 4);

  wxform_offsets_kernel<<<dim3(192 + SCAN_BLOCKS), dim3(256), 0, stream>>>(W, split, Bt, offsets);
  sums_kernel<<<dim3(N_MOLS / 4), dim3(256), 0, stream>>>(x, offsets, S);
  gemm_bias_tanh_kernel<<<dim3(N_MOLS / 8), dim3(256), 0, stream>>>(S, Bt, bias, out);
}